// Round 13
// baseline (3352.171 us; speedup 1.0000x reference)
//
#include <hip/hip_runtime.h>
#include <stdint.h>

// LSTMTimeDecoder on MI355X — round 13.
// G=4 pipeline: 64 wgs x 16 members; each wg interleaves FOUR batch-groups.
// Prefetch issued 2 slots ahead (~1600cy cover >= L3 RT), so consume data is
// architecturally complete (retired by an intervening slot's vmcnt(0)) — no
// consume waitcnt; sentinel check only (+ rare retry). Repoison early
// (post-validation), retired by pre-F vmcnt(0) that hides under compute.
// W_hh in asm-pinned register arrays (static unroll, no lambdas/refs —
// round-12's crash suspect removed). k_out split (round-11-verified).

#define HD 512
#define BD 256
#define SD 512
#define OD 128
#define SENT 0xFF80FF80u

typedef __attribute__((ext_vector_type(8))) short short8;
typedef __attribute__((ext_vector_type(4))) float f32x4;
typedef __attribute__((ext_vector_type(4))) unsigned int u32x4;

static __device__ __forceinline__ unsigned short f2bf(float x) {
  unsigned int u = __float_as_uint(x);
  u += 0x7fffu + ((u >> 16) & 1u);
  return (unsigned short)(u >> 16);
}
static __device__ __forceinline__ float sigm(float x) {
  return 1.0f / (1.0f + __expf(-x));
}
static __device__ __forceinline__ float tanhf_(float x) {
  x = fminf(15.f, fmaxf(-15.f, x));
  float e = __expf(2.f * x);
  return (e - 1.f) / (e + 1.f);
}
static __device__ __forceinline__ int badchk(u32x4 v) {
  return (v.x == SENT) | (v.y == SENT) | (v.z == SENT) | (v.w == SENT);
}

// ---------------- prep kernels (verified rounds 1-12) ----------------
__global__ __launch_bounds__(256) void k_cvt(const float* __restrict__ whh,
                                             const float* __restrict__ linw,
                                             unsigned short* __restrict__ whhb,
                                             unsigned short* __restrict__ linwb) {
  int i = blockIdx.x * 256 + threadIdx.x;
  whhb[i] = f2bf(whh[i]);
  if (i < OD * HD) linwb[i] = f2bf(linw[i]);
}

__global__ __launch_bounds__(256) void k_td(const float* __restrict__ t,
                                            float* __restrict__ td) {
  int i = blockIdx.x * 256 + threadIdx.x;
  float v = 0.f;
  if (i >= BD) v = t[i] - t[i - BD];
  td[i] = v;
}

__global__ __launch_bounds__(256) void k_u(const float* __restrict__ wih,
                                           const float* __restrict__ tw,
                                           const float* __restrict__ tb,
                                           const float* __restrict__ bih,
                                           const float* __restrict__ bhh,
                                           float* __restrict__ u,
                                           float* __restrict__ ub) {
  int gc = blockIdx.x * 256 + threadIdx.x;
  const float4* w4 = (const float4*)(wih + (size_t)gc * (2 * HD) + HD);
  const float4* t4 = (const float4*)tw;
  const float4* b4 = (const float4*)tb;
  float a = 0.f, b = 0.f;
  for (int k = 0; k < HD / 4; ++k) {
    float4 w = w4[k], tv = t4[k], bv = b4[k];
    a += w.x * tv.x + w.y * tv.y + w.z * tv.z + w.w * tv.w;
    b += w.x * bv.x + w.y * bv.y + w.z * bv.z + w.w * bv.w;
  }
  u[gc] = a;
  ub[gc] = b + bih[gc] + bhh[gc];
}

__global__ __launch_bounds__(1024) void k_cw(const float* __restrict__ C,
                                             const float* __restrict__ wih,
                                             const float* __restrict__ ub,
                                             float* __restrict__ CW) {
  int gc = blockIdx.x * 64 + (threadIdx.x & 63);
  int b  = blockIdx.y * 16 + (threadIdx.x >> 6);
  const float4* c4 = (const float4*)(C + (size_t)b * HD);
  const float4* w4 = (const float4*)(wih + (size_t)gc * (2 * HD));
  float acc = 0.f;
  for (int k = 0; k < HD / 4; ++k) {
    float4 cv = c4[k], wv = w4[k];
    acc += cv.x * wv.x + cv.y * wv.y + cv.z * wv.z + cv.w * wv.w;
  }
  CW[(size_t)b * (4 * HD) + gc] = acc + ub[gc];
}

__global__ __launch_bounds__(256) void k_poison(unsigned int* __restrict__ hbuf) {
  u32x4 s = {SENT, SENT, SENT, SENT};
  unsigned int* p = hbuf + (size_t)(blockIdx.x * 256 + threadIdx.x) * 4;
  asm volatile("global_store_dwordx4 %0, %1, off sc0 sc1" :: "v"(p), "v"(s) : "memory");
}

// ---------------- main recurrent kernel (G=4) ----------------
__global__ __launch_bounds__(256, 1) void k_main(
    const float* __restrict__ CW, const float* __restrict__ u,
    const float* __restrict__ td, const unsigned short* __restrict__ whhb,
    unsigned short* __restrict__ hbuf, unsigned short* __restrict__ hs)
{
  __shared__ __align__(16) unsigned short hlds[16 * HD];  // 16KB swizzled image
  __shared__ float gbuf[4][16][33];

  const int tid  = threadIdx.x;
  const int lane = tid & 63;
  const int wv   = tid >> 6;          // wave == gate i,f,g,o
  const int m    = blockIdx.x & 15;   // member: h-cols [m*32, m*32+32)
  const int q    = blockIdx.x >> 4;   // 0..3 ; groups {q, q+4, q+8, q+12}

  // ---- W_hh fragments -> register arrays via asm (static unrolled) ----
  short8 w0[16], w1[16];
  {
    const unsigned short* wb =
        whhb + ((size_t)wv * HD + m * 32 + (lane & 15)) * HD + (lane >> 4) * 8;
    #pragma unroll
    for (int kk = 0; kk < 16; ++kk) {
      asm volatile("global_load_dwordx4 %0, %2, off\n\t"
                   "global_load_dwordx4 %1, %3, off"
                   : "=&v"(w0[kk]), "=&v"(w1[kk])
                   : "v"(wb + kk * 32), "v"(wb + 16 * HD + kk * 32) : "memory");
    }
  }

  const int r    = tid >> 4;
  const int jl0  = (tid & 15) * 2;
  const int col0 = m * 32 + jl0;
  const int foff = r * 1024 + (((col0 >> 3) ^ (r & 7)) << 4) + ((col0 * 2) & 15);
  const int arow = lane & 15, akoff = lane >> 4, axor = arow & 7;

  int   grow[4];
  char* hb[4];
  float cwr[4][8], ur[8];
  float cs0[4] = {0.f, 0.f, 0.f, 0.f}, cs1[4] = {0.f, 0.f, 0.f, 0.f};
  float tdn[4] = {0.f, 0.f, 0.f, 0.f};
  u32x4 vp[4][4];

  #pragma unroll
  for (int gi = 0; gi < 4; ++gi) {
    int g = q + 4 * gi;
    grow[gi] = g * 16 + r;
    hb[gi] = (char*)hbuf + (size_t)g * 49152;   // 3 slots x 16KB
    #pragma unroll
    for (int gg = 0; gg < 4; ++gg) {
      int col = gg * HD + col0;
      cwr[gi][gg * 2]     = CW[(size_t)grow[gi] * (4 * HD) + col];
      cwr[gi][gg * 2 + 1] = CW[(size_t)grow[gi] * (4 * HD) + col + 1];
    }
  }
  #pragma unroll
  for (int gg = 0; gg < 4; ++gg) {
    ur[gg * 2]     = u[gg * HD + col0];
    ur[gg * 2 + 1] = u[gg * HD + col0 + 1];
  }

  asm volatile("s_waitcnt vmcnt(0)" ::: "memory");   // W + constants resident
  __builtin_amdgcn_sched_barrier(0);
  __syncthreads();

  for (int t = 0; t < SD; ++t) {
    const size_t oC = (size_t)(t % 3) * 16384;
    const size_t oN = (size_t)((t + 1) % 3) * 16384;
    const size_t oR = (size_t)((t + 2) % 3) * 16384;

    #pragma unroll
    for (int j = 0; j < 4; ++j) {
      float tdv = 0.f;

      // ---- consume h_t(g_j): prefetched 2 slots ago, retired by an
      //      intervening pre-F vmcnt(0) => data complete. sched_barrier
      //      pins the compare below the completion point (rule #18). ----
      if (t > 0) {
        asm volatile("s_waitcnt vmcnt(7)" ::: "memory");   // defensive no-op
        __builtin_amdgcn_sched_barrier(0);
        tdv = tdn[j];
        int p0 = badchk(vp[j][0]), p1 = badchk(vp[j][1]),
            p2 = badchk(vp[j][2]), p3 = badchk(vp[j][3]);
        if (p0 | p1 | p2 | p3) {            // peer >2 slots behind: rare
          const char* src = hb[j] + oC + (size_t)tid * 16;
          int guard = 0;
          do {
            if (++guard > (1 << 16)) break;
            __builtin_amdgcn_s_sleep(1);
            asm volatile(
                "global_load_dwordx4 %0, %4, off sc0 sc1\n\t"
                "global_load_dwordx4 %1, %5, off sc0 sc1\n\t"
                "global_load_dwordx4 %2, %6, off sc0 sc1\n\t"
                "global_load_dwordx4 %3, %7, off sc0 sc1\n\t"
                "s_waitcnt vmcnt(0)"
                : "=&v"(vp[j][0]), "=&v"(vp[j][1]), "=&v"(vp[j][2]), "=&v"(vp[j][3])
                : "v"(src), "v"(src + 4096), "v"(src + 8192), "v"(src + 12288)
                : "memory");
            __builtin_amdgcn_sched_barrier(0);
            p0 = badchk(vp[j][0]); p1 = badchk(vp[j][1]);
            p2 = badchk(vp[j][2]); p3 = badchk(vp[j][3]);
          } while (p0 | p1 | p2 | p3);
        }
        *(u32x4*)((char*)hlds + (size_t)tid * 16)         = vp[j][0];
        *(u32x4*)((char*)hlds + 4096 + (size_t)tid * 16)  = vp[j][1];
        *(u32x4*)((char*)hlds + 8192 + (size_t)tid * 16)  = vp[j][2];
        *(u32x4*)((char*)hlds + 12288 + (size_t)tid * 16) = vp[j][3];
      }

      // ---- early repoison (legal: consume validated h_t => peers done
      //      reading h_{t-1}); ack hides under barriers+gates+cell ----
      {
        char* pp = hb[j] + oR + (size_t)m * 1024 + (size_t)tid * 4;
        unsigned int s = SENT;
        asm volatile("global_store_dword %0, %1, off sc0 sc1" :: "v"(pp), "v"(s) : "memory");
      }
      asm volatile("s_waitcnt lgkmcnt(0)" ::: "memory");
      __builtin_amdgcn_s_barrier();          // A: hlds ready

      // ---- gates = h_t @ W^T : A from hlds (XOR addr), B = registers ----
      f32x4 acc0 = {0.f, 0.f, 0.f, 0.f}, acc1 = {0.f, 0.f, 0.f, 0.f};
      if (t > 0) {
        #pragma unroll
        for (int kk = 0; kk < 16; ++kk) {
          short8 a = *(const short8*)((const char*)hlds + (size_t)arow * 1024 +
                                      (size_t)(((kk * 4 + akoff) ^ axor) << 4));
          acc0 = __builtin_amdgcn_mfma_f32_16x16x32_bf16(a, w0[kk], acc0, 0, 0, 0);
          acc1 = __builtin_amdgcn_mfma_f32_16x16x32_bf16(a, w1[kk], acc1, 0, 0, 0);
        }
      }
      {
        int rr = (lane >> 4) * 4, cc = lane & 15;
        #pragma unroll
        for (int qq = 0; qq < 4; ++qq) {
          gbuf[wv][rr + qq][cc]      = acc0[qq];
          gbuf[wv][rr + qq][16 + cc] = acc1[qq];
        }
      }
      asm volatile("s_waitcnt lgkmcnt(0)" ::: "memory");
      __builtin_amdgcn_s_barrier();          // B: gbuf ready

      // ---- cell (2 elems/thread) ----
      unsigned int hp;
      {
        float p0i = gbuf[0][r][jl0]     + cwr[j][0] + tdv * ur[0];
        float p1i = gbuf[0][r][jl0 + 1] + cwr[j][1] + tdv * ur[1];
        float p0f = gbuf[1][r][jl0]     + cwr[j][2] + tdv * ur[2];
        float p1f = gbuf[1][r][jl0 + 1] + cwr[j][3] + tdv * ur[3];
        float p0g = gbuf[2][r][jl0]     + cwr[j][4] + tdv * ur[4];
        float p1g = gbuf[2][r][jl0 + 1] + cwr[j][5] + tdv * ur[5];
        float p0o = gbuf[3][r][jl0]     + cwr[j][6] + tdv * ur[6];
        float p1o = gbuf[3][r][jl0 + 1] + cwr[j][7] + tdv * ur[7];
        cs0[j] = sigm(p0f) * cs0[j] + sigm(p0i) * tanhf_(p0g);
        cs1[j] = sigm(p1f) * cs1[j] + sigm(p1i) * tanhf_(p1g);
        float h0 = sigm(p0o) * tanhf_(cs0[j]);
        float h1 = sigm(p1o) * tanhf_(cs1[j]);
        hp = (unsigned int)f2bf(h0) | ((unsigned int)f2bf(h1) << 16);
      }

      // ---- pre-F drain: retires repoison (+old stragglers); hidden ----
      asm volatile("s_waitcnt vmcnt(0)" ::: "memory");
      __builtin_amdgcn_sched_barrier(0);

      // ---- F: h_{t+1}(g_j) exchange store (swizzled offset) ----
      {
        char* hsl = hb[j] + oN + foff;
        asm volatile("global_store_dword %0, %1, off sc0 sc1" :: "v"(hsl), "v"(hp) : "memory");
      }
      // ---- F2: hs row for k_out ----
      {
        unsigned short* hd = hs + ((size_t)t * BD + grow[j]) * HD + col0;
        asm volatile("global_store_dword %0, %1, off" :: "v"(hd), "v"(hp) : "memory");
      }
      // ---- C4: prefetch for slot 2-ahead: tj=(j+2)&3, step t (j<2) / t+1 ----
      {
        const int tj = (j + 2) & 3;
        const size_t so = (j < 2) ? oC : oN;
        const char* src = hb[tj] + so + (size_t)tid * 16;
        asm volatile(
            "global_load_dwordx4 %0, %4, off sc0 sc1\n\t"
            "global_load_dwordx4 %1, %5, off sc0 sc1\n\t"
            "global_load_dwordx4 %2, %6, off sc0 sc1\n\t"
            "global_load_dwordx4 %3, %7, off sc0 sc1"
            : "=&v"(vp[tj][0]), "=&v"(vp[tj][1]), "=&v"(vp[tj][2]), "=&v"(vp[tj][3])
            : "v"(src), "v"(src + 4096), "v"(src + 8192), "v"(src + 12288)
            : "memory");
      }
      // ---- td prefetch (own group, next step) ----
      {
        int tt = (t + 1 < SD) ? (t + 1) : t;
        const float* ta = td + (size_t)tt * BD + grow[j];
        asm volatile("global_load_dword %0, %1, off" : "=&v"(tdn[j]) : "v"(ta) : "memory");
      }
    }
  }
}

// ---------------- output projection (round-11-verified) ----------------
__global__ __launch_bounds__(256) void k_out(const unsigned short* __restrict__ hs,
                                             const unsigned short* __restrict__ linwb,
                                             const float* __restrict__ linb,
                                             float* __restrict__ out) {
  const int tid  = threadIdx.x;
  const int lane = tid & 63;
  const int w    = tid >> 6;
  const size_t R0 = (size_t)blockIdx.x * 64 + (size_t)w * 16;

  short8 a[16];
  {
    const unsigned short* ab = hs + (R0 + (lane & 15)) * HD + (lane >> 4) * 8;
    #pragma unroll
    for (int kk = 0; kk < 16; ++kk) a[kk] = *(const short8*)(ab + kk * 32);
  }

  f32x4 acc[8];
  #pragma unroll
  for (int j = 0; j < 8; ++j) acc[j] = (f32x4){0.f, 0.f, 0.f, 0.f};

  #pragma unroll 4
  for (int kk = 0; kk < 16; ++kk) {
    #pragma unroll
    for (int j = 0; j < 8; ++j) {
      const unsigned short* bb =
          linwb + (size_t)(j * 16 + (lane & 15)) * HD + kk * 32 + (lane >> 4) * 8;
      short8 b = *(const short8*)bb;
      acc[j] = __builtin_amdgcn_mfma_f32_16x16x32_bf16(a[kk], b, acc[j], 0, 0, 0);
    }
  }

  const int rr = (lane >> 4) * 4, cc = lane & 15;
  #pragma unroll
  for (int j = 0; j < 8; ++j) {
    float lb = linb[j * 16 + cc];
    #pragma unroll
    for (int qq = 0; qq < 4; ++qq)
      out[(R0 + rr + qq) * OD + j * 16 + cc] = acc[j][qq] + lb;
  }
}

// ---------------- launcher ----------------
extern "C" void kernel_launch(void* const* d_in, const int* in_sizes, int n_in,
                              void* d_out, int out_size, void* d_ws, size_t ws_size,
                              hipStream_t stream) {
  const float* C    = (const float*)d_in[0];
  const float* t    = (const float*)d_in[1];
  // d_in[2] = mask (unused by reference)
  const float* Wih  = (const float*)d_in[3];
  const float* Whh  = (const float*)d_in[4];
  const float* bih  = (const float*)d_in[5];
  const float* bhh  = (const float*)d_in[6];
  const float* linW = (const float*)d_in[7];
  const float* linb = (const float*)d_in[8];
  const float* tW   = (const float*)d_in[9];
  const float* tb   = (const float*)d_in[10];
  float* out = (float*)d_out;

  char* ws = (char*)d_ws;
  float*          CW    = (float*)(ws + 0);                 // 2,097,152
  float*          u     = (float*)(ws + 2097152);           // 8,192
  float*          ub    = (float*)(ws + 2105344);           // 8,192
  float*          td    = (float*)(ws + 2113536);           // 524,288
  unsigned short* whhb  = (unsigned short*)(ws + 2637824);  // 2,097,152
  unsigned short* linwb = (unsigned short*)(ws + 4734976);  // 131,072
  unsigned short* hbuf  = (unsigned short*)(ws + 4866048);  // 786,432
  unsigned short* hs    = (unsigned short*)(ws + 5652480);  // 134,217,728
  if (ws_size < 5652480ull + 134217728ull) return;

  k_poison<<<192, 256, 0, stream>>>((unsigned int*)hbuf);
  k_cvt<<<4096, 256, 0, stream>>>(Whh, linW, whhb, linwb);
  k_td <<<512, 256, 0, stream>>>(t, td);
  k_u  <<<8, 256, 0, stream>>>(Wih, tW, tb, bih, bhh, u, ub);
  k_cw <<<dim3(32, 16), 1024, 0, stream>>>(C, Wih, ub, CW);
  k_main<<<64, 256, 0, stream>>>(CW, u, td, whhb, hbuf, hs);
  k_out<<<2048, 256, 0, stream>>>(hs, linwb, linb, out);
}

// Round 14
// 1855.934 us; speedup vs baseline: 1.8062x; 1.8062x over previous
//
#include <hip/hip_runtime.h>
#include <stdint.h>

// LSTMTimeDecoder on MI355X — round 14.
// G-scaling data (r9/r10/r13): per-step cost 8.8k/9.0k/14.3k cy for G=1/2/4 —
// slot work floor ~3.3k cy doesn't shrink, so G>1 multiplies it. G=1 wins IF
// the exposed exchange latency (~5.5k cy in r9) drops to ~1 RT. r9's failure
// was calibration: sleep(4)=256cy first-poll delay vs ~600-900cy store-landing
// => retry storms. This round: G=1 (256 wgs), load-early/check-late with an
// ~850cy delay window filled by the inline out-projection (wave wsel) or
// s_sleep(13); W_hh in asm-pinned registers (halves slot LDS work — on the
// critical path at G=1); masked per-chunk retries. Exchange protocol
// (swizzled image, sentinel, 3-slot, sc0sc1, early repoison) = r11/r13
// verified, byte-identical. No hs buffer / k_out (inline out-proj).

#define HD 512
#define BD 256
#define SD 512
#define OD 128
#define SENT 0xFF80FF80u

typedef __attribute__((ext_vector_type(8))) short short8;
typedef __attribute__((ext_vector_type(4))) float f32x4;
typedef __attribute__((ext_vector_type(4))) unsigned int u32x4;

static __device__ __forceinline__ unsigned short f2bf(float x) {
  unsigned int u = __float_as_uint(x);
  u += 0x7fffu + ((u >> 16) & 1u);
  return (unsigned short)(u >> 16);
}
static __device__ __forceinline__ float sigm(float x) {
  return 1.0f / (1.0f + __expf(-x));
}
static __device__ __forceinline__ float tanhf_(float x) {
  x = fminf(15.f, fmaxf(-15.f, x));
  float e = __expf(2.f * x);
  return (e - 1.f) / (e + 1.f);
}
static __device__ __forceinline__ int badchk(u32x4 v) {
  return (v.x == SENT) | (v.y == SENT) | (v.z == SENT) | (v.w == SENT);
}

// ---------------- prep kernels (verified rounds 1-13) ----------------
__global__ __launch_bounds__(256) void k_cvt(const float* __restrict__ whh,
                                             const float* __restrict__ linw,
                                             unsigned short* __restrict__ whhb,
                                             unsigned short* __restrict__ linwb) {
  int i = blockIdx.x * 256 + threadIdx.x;
  whhb[i] = f2bf(whh[i]);
  if (i < OD * HD) linwb[i] = f2bf(linw[i]);
}

__global__ __launch_bounds__(256) void k_td(const float* __restrict__ t,
                                            float* __restrict__ td) {
  int i = blockIdx.x * 256 + threadIdx.x;
  float v = 0.f;
  if (i >= BD) v = t[i] - t[i - BD];
  td[i] = v;
}

__global__ __launch_bounds__(256) void k_u(const float* __restrict__ wih,
                                           const float* __restrict__ tw,
                                           const float* __restrict__ tb,
                                           const float* __restrict__ bih,
                                           const float* __restrict__ bhh,
                                           float* __restrict__ u,
                                           float* __restrict__ ub) {
  int gc = blockIdx.x * 256 + threadIdx.x;
  const float4* w4 = (const float4*)(wih + (size_t)gc * (2 * HD) + HD);
  const float4* t4 = (const float4*)tw;
  const float4* b4 = (const float4*)tb;
  float a = 0.f, b = 0.f;
  for (int k = 0; k < HD / 4; ++k) {
    float4 w = w4[k], tv = t4[k], bv = b4[k];
    a += w.x * tv.x + w.y * tv.y + w.z * tv.z + w.w * tv.w;
    b += w.x * bv.x + w.y * bv.y + w.z * bv.z + w.w * bv.w;
  }
  u[gc] = a;
  ub[gc] = b + bih[gc] + bhh[gc];
}

__global__ __launch_bounds__(1024) void k_cw(const float* __restrict__ C,
                                             const float* __restrict__ wih,
                                             const float* __restrict__ ub,
                                             float* __restrict__ CW) {
  int gc = blockIdx.x * 64 + (threadIdx.x & 63);
  int b  = blockIdx.y * 16 + (threadIdx.x >> 6);
  const float4* c4 = (const float4*)(C + (size_t)b * HD);
  const float4* w4 = (const float4*)(wih + (size_t)gc * (2 * HD));
  float acc = 0.f;
  for (int k = 0; k < HD / 4; ++k) {
    float4 cv = c4[k], wv = w4[k];
    acc += cv.x * wv.x + cv.y * wv.y + cv.z * wv.z + cv.w * wv.w;
  }
  CW[(size_t)b * (4 * HD) + gc] = acc + ub[gc];
}

__global__ __launch_bounds__(256) void k_poison(unsigned int* __restrict__ hbuf) {
  u32x4 s = {SENT, SENT, SENT, SENT};
  unsigned int* p = hbuf + (size_t)(blockIdx.x * 256 + threadIdx.x) * 4;
  asm volatile("global_store_dwordx4 %0, %1, off sc0 sc1" :: "v"(p), "v"(s) : "memory");
}

// ---------------- main recurrent kernel (G=1, calibrated) ----------------
__global__ __launch_bounds__(256, 1) void k_main(
    const float* __restrict__ CW, const float* __restrict__ u,
    const float* __restrict__ td, const unsigned short* __restrict__ whhb,
    const unsigned short* __restrict__ linwb, const float* __restrict__ linb,
    unsigned short* __restrict__ hbuf, float* __restrict__ out)
{
  __shared__ __align__(16) unsigned short hlds[16 * HD];   // 16KB swizzled image
  __shared__ __align__(16) unsigned short lwlds[16 * HD];  // 16KB linW slice
  __shared__ float gbuf[4][16][33];

  const int tid  = threadIdx.x;
  const int lane = tid & 63;
  const int wv   = tid >> 6;          // wave == gate i,f,g,o
  const int gid  = blockIdx.x & 15;   // batch group
  const int m    = blockIdx.x >> 4;   // member: h-cols [m*32, m*32+32)

  // ---- W_hh fragments -> registers via asm (r11-verified layout) ----
  short8 w0[16], w1[16];
  {
    const unsigned short* wb =
        whhb + ((size_t)wv * HD + m * 32 + (lane & 15)) * HD + (lane >> 4) * 8;
    #pragma unroll
    for (int kk = 0; kk < 16; ++kk) {
      asm volatile("global_load_dwordx4 %0, %2, off\n\t"
                   "global_load_dwordx4 %1, %3, off"
                   : "=&v"(w0[kk]), "=&v"(w1[kk])
                   : "v"(wb + kk * 32), "v"(wb + 16 * HD + kk * 32) : "memory");
    }
  }

  // ---- linW slice -> LDS (r6 Wlds staging pattern, 16 rows) ----
  if (m < 8) {
    for (int i = tid; i < 16 * 64; i += 256) {
      int rl = i >> 6, c = i & 63;
      *(short8*)((char*)lwlds + (size_t)rl * 1024 + (size_t)c * 16) =
          *(const short8*)((const char*)linwb + (size_t)(m * 16 + rl) * 1024 +
                           (size_t)((c ^ (rl & 7)) * 16));
    }
  }

  // ---- per-thread cell constants ----
  const int r    = tid >> 4;
  const int jl0  = (tid & 15) * 2;
  const int grow = gid * 16 + r;
  const int col0 = m * 32 + jl0;
  const int foff = r * 1024 + (((col0 >> 3) ^ (r & 7)) << 4) + ((col0 * 2) & 15);
  float cwr[8], ur[8];
  #pragma unroll
  for (int g = 0; g < 4; ++g) {
    int col = g * HD + col0;
    cwr[g * 2]     = CW[(size_t)grow * (4 * HD) + col];
    cwr[g * 2 + 1] = CW[(size_t)grow * (4 * HD) + col + 1];
    ur[g * 2]      = u[col];
    ur[g * 2 + 1]  = u[col + 1];
  }
  float cs0 = 0.f, cs1 = 0.f;

  const int  wsel  = 1 + (m % 3);
  const bool owsel = (m < 8) && (wv == wsel);
  float lb = 0.f;
  if (m < 8) lb = linb[m * 16 + (lane & 15)];

  char* hb = (char*)hbuf + (size_t)gid * 49152;   // 3 slots x 16KB

  const int arow  = lane & 15;
  const int akoff = lane >> 4;
  const int axor  = arow & 7;
  // out-proj / gates A-read share: addr(kk) = arow*1024 + (((kk*4+akoff)^axor)<<4)
  const int lrow  = lane & 15;                 // out-proj B row
  const int lxor  = (lrow & 7) << 4;

  u32x4 v0, v1, v2, v3;
  float tdn = 0.f, tdv = 0.f;

  asm volatile("s_waitcnt vmcnt(0)" ::: "memory");   // W + constants resident
  __builtin_amdgcn_sched_barrier(0);
  __syncthreads();                                    // also covers lwlds

  for (int t = 0; t < SD; ++t) {
    const size_t oN = (size_t)((t + 1) % 3) * 16384;  // h_{t+1} slot
    const size_t oR = (size_t)(t % 3) * 16384;        // repoison target

    // ---- (a) gates = h_t @ W^T (A from hlds XOR-read, B = registers) ----
    f32x4 acc0 = {0.f, 0.f, 0.f, 0.f}, acc1 = {0.f, 0.f, 0.f, 0.f};
    if (t > 0) {
      #pragma unroll
      for (int kk = 0; kk < 16; ++kk) {
        short8 a = *(const short8*)((const char*)hlds + (size_t)arow * 1024 +
                                    (size_t)(((kk * 4 + akoff) ^ axor) << 4));
        acc0 = __builtin_amdgcn_mfma_f32_16x16x32_bf16(a, w0[kk], acc0, 0, 0, 0);
        acc1 = __builtin_amdgcn_mfma_f32_16x16x32_bf16(a, w1[kk], acc1, 0, 0, 0);
      }
    }
    {
      int rr = (lane >> 4) * 4, cc = lane & 15;
      #pragma unroll
      for (int qq = 0; qq < 4; ++qq) {
        gbuf[wv][rr + qq][cc]      = acc0[qq];
        gbuf[wv][rr + qq][16 + cc] = acc1[qq];
      }
    }
    asm volatile("s_waitcnt lgkmcnt(0)" ::: "memory");
    __builtin_amdgcn_s_barrier();          // B1: gbuf ready

    // ---- (c) cell (2 elems/thread) ----
    unsigned int hp;
    {
      float p0i = gbuf[0][r][jl0]     + cwr[0] + tdv * ur[0];
      float p1i = gbuf[0][r][jl0 + 1] + cwr[1] + tdv * ur[1];
      float p0f = gbuf[1][r][jl0]     + cwr[2] + tdv * ur[2];
      float p1f = gbuf[1][r][jl0 + 1] + cwr[3] + tdv * ur[3];
      float p0g = gbuf[2][r][jl0]     + cwr[4] + tdv * ur[4];
      float p1g = gbuf[2][r][jl0 + 1] + cwr[5] + tdv * ur[5];
      float p0o = gbuf[3][r][jl0]     + cwr[6] + tdv * ur[6];
      float p1o = gbuf[3][r][jl0 + 1] + cwr[7] + tdv * ur[7];
      cs0 = sigm(p0f) * cs0 + sigm(p0i) * tanhf_(p0g);
      cs1 = sigm(p1f) * cs1 + sigm(p1i) * tanhf_(p1g);
      float h0 = sigm(p0o) * tanhf_(cs0);
      float h1 = sigm(p1o) * tanhf_(cs1);
      hp = (unsigned int)f2bf(h0) | ((unsigned int)f2bf(h1) << 16);
    }

    // ---- (d) F: h_{t+1} exchange store (swizzled offset) ----
    {
      char* hsl = hb + oN + foff;
      asm volatile("global_store_dword %0, %1, off sc0 sc1" :: "v"(hsl), "v"(hp) : "memory");
    }

    // ---- (e1) issue consume loads + td load NOW (land during delay window) ----
    {
      const char* src = hb + oN + (size_t)tid * 16;
      asm volatile(
          "global_load_dwordx4 %0, %4, off sc0 sc1\n\t"
          "global_load_dwordx4 %1, %5, off sc0 sc1\n\t"
          "global_load_dwordx4 %2, %6, off sc0 sc1\n\t"
          "global_load_dwordx4 %3, %7, off sc0 sc1"
          : "=&v"(v0), "=&v"(v1), "=&v"(v2), "=&v"(v3)
          : "v"(src), "v"(src + 4096), "v"(src + 8192), "v"(src + 12288)
          : "memory");
      int tt = (t + 1 < SD) ? (t + 1) : t;
      const float* ta = td + (size_t)tt * BD + grow;
      asm volatile("global_load_dword %0, %1, off" : "=&v"(tdn) : "v"(ta) : "memory");
    }

    // ---- (e2) delay window: out-proj row t-1 (wsel wave) or sleep ----
    if (owsel && t > 0) {
      f32x4 osA = {0.f, 0.f, 0.f, 0.f}, osB = {0.f, 0.f, 0.f, 0.f};
      #pragma unroll
      for (int kk = 0; kk < 8; ++kk) {
        short8 aA = *(const short8*)((const char*)hlds + (size_t)arow * 1024 +
                                     (size_t)(((kk * 4 + akoff) ^ axor) << 4));
        short8 aB = *(const short8*)((const char*)hlds + (size_t)arow * 1024 +
                                     (size_t)((((kk + 8) * 4 + akoff) ^ axor) << 4));
        short8 bA = *(const short8*)((const char*)lwlds + (size_t)lrow * 1024 +
                                     (size_t)((kk * 64 + akoff * 16) ^ lxor));
        short8 bB = *(const short8*)((const char*)lwlds + (size_t)lrow * 1024 +
                                     (size_t)(((kk + 8) * 64 + akoff * 16) ^ lxor));
        osA = __builtin_amdgcn_mfma_f32_16x16x32_bf16(aA, bA, osA, 0, 0, 0);
        osB = __builtin_amdgcn_mfma_f32_16x16x32_bf16(aB, bB, osB, 0, 0, 0);
      }
      float* ob = out + (size_t)(t - 1) * (BD * OD) + (size_t)(gid * 16) * OD + m * 16;
      int rr = (lane >> 4) * 4, cc = lane & 15;
      #pragma unroll
      for (int qq = 0; qq < 4; ++qq) {
        float vst = osA[qq] + osB[qq] + lb;
        float* oa = ob + (size_t)(rr + qq) * OD + cc;
        asm volatile("global_store_dword %0, %1, off" :: "v"(oa), "v"(vst) : "memory");
      }
    } else {
      __builtin_amdgcn_s_sleep(13);    // ~832 cy: covers peers' store landing
    }

    // ---- (f) wait: everything in flight landed; (g) validate + retry ----
    asm volatile("s_waitcnt vmcnt(0)" ::: "memory");
    __builtin_amdgcn_sched_barrier(0);
    {
      int p0 = badchk(v0), p1 = badchk(v1), p2 = badchk(v2), p3 = badchk(v3);
      int guard = 0;
      while (p0 | p1 | p2 | p3) {
        if (++guard > (1 << 16)) break;  // bounded: garbage-not-hang
        __builtin_amdgcn_s_sleep(2);     // ~128 cy backoff
        const char* src = hb + oN + (size_t)tid * 16;
        if (p0) asm volatile("global_load_dwordx4 %0, %1, off sc0 sc1" : "=&v"(v0) : "v"(src) : "memory");
        if (p1) asm volatile("global_load_dwordx4 %0, %1, off sc0 sc1" : "=&v"(v1) : "v"(src + 4096) : "memory");
        if (p2) asm volatile("global_load_dwordx4 %0, %1, off sc0 sc1" : "=&v"(v2) : "v"(src + 8192) : "memory");
        if (p3) asm volatile("global_load_dwordx4 %0, %1, off sc0 sc1" : "=&v"(v3) : "v"(src + 12288) : "memory");
        asm volatile("s_waitcnt vmcnt(0)" ::: "memory");
        __builtin_amdgcn_sched_barrier(0);
        p0 = badchk(v0); p1 = badchk(v1); p2 = badchk(v2); p3 = badchk(v3);
      }
    }

    // ---- (h) repoison slot t%3 (justified: h_{t+1} validated => peers done
    //      reading h_t); retired by next iter's (f) vmcnt(0) ----
    {
      char* pp = hb + oR + (size_t)m * 1024 + (size_t)tid * 4;
      unsigned int s = SENT;
      asm volatile("global_store_dword %0, %1, off sc0 sc1" :: "v"(pp), "v"(s) : "memory");
    }

    __builtin_amdgcn_s_barrier();          // B3: hlds reads (out-proj) done

    // ---- (i) scatter h_{t+1} into hlds (linear: image pre-swizzled) ----
    *(u32x4*)((char*)hlds + (size_t)tid * 16)         = v0;
    *(u32x4*)((char*)hlds + 4096 + (size_t)tid * 16)  = v1;
    *(u32x4*)((char*)hlds + 8192 + (size_t)tid * 16)  = v2;
    *(u32x4*)((char*)hlds + 12288 + (size_t)tid * 16) = v3;
    asm volatile("s_waitcnt lgkmcnt(0)" ::: "memory");
    __builtin_amdgcn_s_barrier();          // B2: hlds = h_{t+1}

    tdv = tdn;
  }

  // ---- tail: out row SD-1 (hlds = h_SD) ----
  if (owsel) {
    f32x4 osA = {0.f, 0.f, 0.f, 0.f}, osB = {0.f, 0.f, 0.f, 0.f};
    #pragma unroll
    for (int kk = 0; kk < 8; ++kk) {
      short8 aA = *(const short8*)((const char*)hlds + (size_t)arow * 1024 +
                                   (size_t)(((kk * 4 + akoff) ^ axor) << 4));
      short8 aB = *(const short8*)((const char*)hlds + (size_t)arow * 1024 +
                                   (size_t)((((kk + 8) * 4 + akoff) ^ axor) << 4));
      short8 bA = *(const short8*)((const char*)lwlds + (size_t)lrow * 1024 +
                                   (size_t)((kk * 64 + akoff * 16) ^ lxor));
      short8 bB = *(const short8*)((const char*)lwlds + (size_t)lrow * 1024 +
                                   (size_t)(((kk + 8) * 64 + akoff * 16) ^ lxor));
      osA = __builtin_amdgcn_mfma_f32_16x16x32_bf16(aA, bA, osA, 0, 0, 0);
      osB = __builtin_amdgcn_mfma_f32_16x16x32_bf16(aB, bB, osB, 0, 0, 0);
    }
    float* ob = out + (size_t)(SD - 1) * (BD * OD) + (size_t)(gid * 16) * OD + m * 16;
    int rr = (lane >> 4) * 4, cc = lane & 15;
    #pragma unroll
    for (int qq = 0; qq < 4; ++qq) {
      float vst = osA[qq] + osB[qq] + lb;
      float* oa = ob + (size_t)(rr + qq) * OD + cc;
      asm volatile("global_store_dword %0, %1, off" :: "v"(oa), "v"(vst) : "memory");
    }
  }
}

// ---------------- launcher ----------------
extern "C" void kernel_launch(void* const* d_in, const int* in_sizes, int n_in,
                              void* d_out, int out_size, void* d_ws, size_t ws_size,
                              hipStream_t stream) {
  const float* C    = (const float*)d_in[0];
  const float* t    = (const float*)d_in[1];
  // d_in[2] = mask (unused by reference)
  const float* Wih  = (const float*)d_in[3];
  const float* Whh  = (const float*)d_in[4];
  const float* bih  = (const float*)d_in[5];
  const float* bhh  = (const float*)d_in[6];
  const float* linW = (const float*)d_in[7];
  const float* linb = (const float*)d_in[8];
  const float* tW   = (const float*)d_in[9];
  const float* tb   = (const float*)d_in[10];
  float* out = (float*)d_out;

  char* ws = (char*)d_ws;
  float*          CW    = (float*)(ws + 0);                 // 2,097,152
  float*          u     = (float*)(ws + 2097152);           // 8,192
  float*          ub    = (float*)(ws + 2105344);           // 8,192
  float*          td    = (float*)(ws + 2113536);           // 524,288
  unsigned short* whhb  = (unsigned short*)(ws + 2637824);  // 2,097,152
  unsigned short* linwb = (unsigned short*)(ws + 4734976);  // 131,072
  unsigned short* hbuf  = (unsigned short*)(ws + 4866048);  // 786,432
  if (ws_size < 5652480) return;

  k_poison<<<192, 256, 0, stream>>>((unsigned int*)hbuf);
  k_cvt<<<4096, 256, 0, stream>>>(Whh, linW, whhb, linwb);
  k_td <<<512, 256, 0, stream>>>(t, td);
  k_u  <<<8, 256, 0, stream>>>(Wih, tW, tb, bih, bhh, u, ub);
  k_cw <<<dim3(32, 16), 1024, 0, stream>>>(C, Wih, ub, CW);
  k_main<<<256, 256, 0, stream>>>(CW, u, td, whhb, linwb, linb, hbuf, out);
}